// Round 5
// baseline (2967.425 us; speedup 1.0000x reference)
//
#include <hip/hip_runtime.h>

// LSTM_38869454028951: B=512, T=365, F=16, H=256, 2 layers + linear head.
// Round 5: software-pipelined sync. 16 bg x 16 ns = 256 WGs x 512 thr, 1 WG/CU.
// Body t: P1-GEMM(h1_{t-1},x_t) -> publish h1_t | restage h2_{t-3} (hidden RTT)
//         P2-GEMM(h1_{t-2},h2_{t-3}) -> publish h2_{t-2} | restage h1_t (hidden)
// Sum-counter milestones (1 atomic add/WG/phase), s_sleep polls.
// LDS A row: [h1 slot0 | h1 slot1 | x | h2] = 800 cols (+8 pad).

#define T_STEPS 365
#define ASTR 808   // A row stride in ushorts; 404 words % 32 == 20 -> 2-way reads

typedef __attribute__((ext_vector_type(8))) short short8;
typedef __attribute__((ext_vector_type(8))) unsigned short ushort8;
typedef __attribute__((ext_vector_type(4))) float float4_;
typedef unsigned long long u64;
typedef unsigned int u32;

#define MFMA16(a, b, c) __builtin_amdgcn_mfma_f32_16x16x32_bf16((a), (b), (c), 0, 0, 0)

__device__ __forceinline__ unsigned short f2bf(float v) {
    union { float f; u32 u; } a; a.f = v;
    u32 r = a.u + 0x7fffu + ((a.u >> 16) & 1u);  // RNE
    return (unsigned short)(r >> 16);
}
__device__ __forceinline__ float bf2f(unsigned short h) {
    union { u32 u; float f; } a; a.u = ((u32)h) << 16; return a.f;
}
__device__ __forceinline__ u32 packhl(float v) {
    unsigned short hi = f2bf(v);
    unsigned short lo = f2bf(v - bf2f(hi));
    return ((u32)hi << 16) | (u32)lo;
}
__device__ __forceinline__ float sigm(float x)  { return 1.f / (1.f + __expf(-x)); }
__device__ __forceinline__ float tanh_(float x) { return 2.f / (1.f + __expf(-2.f * x)) - 1.f; }

__device__ __forceinline__ void poll_ge(u32* c, u32 tgt) {
    while (__hip_atomic_load(c, __ATOMIC_RELAXED, __HIP_MEMORY_SCOPE_AGENT) < tgt)
        __builtin_amdgcn_s_sleep(1);
}

// ---------------- prep: blocked hi/lo weights + biases ----------------
// w1blk: [64 tiles][9 ks][16 rows][32 k]; ks<8: Whh1; ks==8: Wih1 (K pad 16->32)
// w2blk: [64][16][16][32]; ks<8: Wih2 (h1 input), ks>=8: Whh2 (h2 input)
__global__ void prep_w(
    const float* __restrict__ Wih1, const float* __restrict__ Whh1,
    const float* __restrict__ bih1, const float* __restrict__ bhh1,
    const float* __restrict__ Wih2, const float* __restrict__ Whh2,
    const float* __restrict__ bih2, const float* __restrict__ bhh2,
    unsigned short* __restrict__ w1h, unsigned short* __restrict__ w1l,
    unsigned short* __restrict__ w2h, unsigned short* __restrict__ w2l,
    float* __restrict__ bias1, float* __restrict__ bias2)
{
    const int tile = blockIdx.x;          // 64
    const int g = tile >> 4, ns = tile & 15;
    const int tid = threadIdx.x;          // 256

    for (int idx = tid; idx < 9 * 512; idx += 256) {
        int ks = idx >> 9, off = idx & 511, r = off >> 5, kk = off & 31;
        int R = g * 256 + ns * 16 + r;
        float v;
        if (ks < 8)       v = Whh1[R * 256 + ks * 32 + kk];
        else if (kk < 16) v = Wih1[R * 16 + kk];
        else              v = 0.f;
        unsigned short h = f2bf(v);
        size_t d = (size_t)(tile * 9 + ks) * 512 + off;
        w1h[d] = h; w1l[d] = f2bf(v - bf2f(h));
    }
    for (int idx = tid; idx < 16 * 512; idx += 256) {
        int ks = idx >> 9, off = idx & 511, r = off >> 5, kk = off & 31;
        int R = g * 256 + ns * 16 + r;
        int k = ks * 32 + kk;
        float v = (k < 256) ? Wih2[R * 256 + k] : Whh2[R * 256 + (k - 256)];
        unsigned short h = f2bf(v);
        size_t d = (size_t)(tile * 16 + ks) * 512 + off;
        w2h[d] = h; w2l[d] = f2bf(v - bf2f(h));
    }
    if (tid < 16) {
        int R = g * 256 + ns * 16 + tid;
        bias1[R] = bih1[R] + bhh1[R];
        bias2[R] = bih2[R] + bhh2[R];
    }
}

// stage 16 packed u32 (8 agent u64 loads) -> bf16 hi/lo LDS (shift unpack)
__device__ __forceinline__ void stage16p(const u32* src, unsigned short* dh, unsigned short* dl) {
    ushort8 H0, H1, L0, L1;
#pragma unroll
    for (int j = 0; j < 4; j++) {
        u64 v = __hip_atomic_load((const u64*)src + j, __ATOMIC_RELAXED, __HIP_MEMORY_SCOPE_AGENT);
        u32 a = (u32)v, b = (u32)(v >> 32);
        H0[2 * j] = (unsigned short)(a >> 16);     L0[2 * j] = (unsigned short)a;
        H0[2 * j + 1] = (unsigned short)(b >> 16); L0[2 * j + 1] = (unsigned short)b;
    }
#pragma unroll
    for (int j = 0; j < 4; j++) {
        u64 v = __hip_atomic_load((const u64*)src + 4 + j, __ATOMIC_RELAXED, __HIP_MEMORY_SCOPE_AGENT);
        u32 a = (u32)v, b = (u32)(v >> 32);
        H1[2 * j] = (unsigned short)(a >> 16);     L1[2 * j] = (unsigned short)a;
        H1[2 * j + 1] = (unsigned short)(b >> 16); L1[2 * j + 1] = (unsigned short)b;
    }
    *(ushort8*)(dh) = H0; *(ushort8*)(dh + 8) = H1;
    *(ushort8*)(dl) = L0; *(ushort8*)(dl + 8) = L1;
}

// ---------------- main ----------------
__global__ __launch_bounds__(512, 2) void lstm_main(
    const float* __restrict__ x,
    const unsigned short* __restrict__ w1h, const unsigned short* __restrict__ w1l,
    const unsigned short* __restrict__ w2h, const unsigned short* __restrict__ w2l,
    const float* __restrict__ bias1, const float* __restrict__ bias2,
    u32* hb1, u32* hb2, u32* prog,
    const float* __restrict__ Wlin, const float* __restrict__ blin,
    float* __restrict__ out)
{
    // A cols: [0..255]=h1 slot0, [256..511]=h1 slot1, [512..543]=x, [544..799]=h2
    __shared__ __align__(16) unsigned short A2h[32][ASTR];
    __shared__ __align__(16) unsigned short A2l[32][ASTR];
    __shared__ __align__(16) float zb[2][32][4][17];   // reused for z1 and z2
    __shared__ __align__(16) float hp[32][17];

    const int tid  = threadIdx.x;
    const int lane = tid & 63;
    const int wv   = tid >> 6;            // 8 waves
    const int quad = lane >> 4;
    const int r16  = lane & 15;
    const int g    = wv & 3;              // gate
    const int kh   = wv >> 2;             // K-half
    const int bg   = blockIdx.x & 15;     // batch group (same XCD for all 16 ns)
    const int ns   = blockIdx.x >> 4;     // col slice
    const int tile = g * 16 + ns;
    const int loff = r16 * 32 + quad * 8;

    // conflict-free updater map: rows {0,16}+{0,4,8,12}+{0..3}, banks {0,16}+r16
    const int urow = ((wv >> 2) << 4) + quad * 4 + (wv & 3);
    const int ucol = r16;
    const int colg = ns * 16 + ucol;

    u32* cnt1 = prog + bg * 32;
    u32* cnt2 = prog + bg * 32 + 1;

    float bi1[4], bi2[4];
#pragma unroll
    for (int gg = 0; gg < 4; gg++) {
        bi1[gg] = bias1[gg * 256 + colg];
        bi2[gg] = bias2[gg * 256 + colg];
    }

    // ---- preload weights (compiler may re-stream from L2 -- that's fine) ----
    const unsigned short* w1h_t = w1h + (size_t)tile * 9 * 512;
    const unsigned short* w1l_t = w1l + (size_t)tile * 9 * 512;
    const unsigned short* w2h_t = w2h + (size_t)tile * 16 * 512;
    const unsigned short* w2l_t = w2l + (size_t)tile * 16 * 512;

    short8 W1H[5], W1L[5], W2H[8], W2L[8];
    if (kh == 0) {
#pragma unroll
        for (int b = 0; b < 5; b++) {      // Whh1 ks 0..4
            W1H[b] = *(const short8*)(w1h_t + (size_t)b * 512 + loff);
            W1L[b] = *(const short8*)(w1l_t + (size_t)b * 512 + loff);
        }
#pragma unroll
        for (int j = 0; j < 8; j++) {      // Wih2 ks 0..7
            W2H[j] = *(const short8*)(w2h_t + (size_t)j * 512 + loff);
            W2L[j] = *(const short8*)(w2l_t + (size_t)j * 512 + loff);
        }
    } else {
#pragma unroll
        for (int b = 0; b < 4; b++) {      // Whh1 ks 5..7 + Wih1 (ks 8)
            W1H[b] = *(const short8*)(w1h_t + (size_t)(5 + b) * 512 + loff);
            W1L[b] = *(const short8*)(w1l_t + (size_t)(5 + b) * 512 + loff);
        }
        W1H[4] = short8{0,0,0,0,0,0,0,0}; W1L[4] = short8{0,0,0,0,0,0,0,0};
#pragma unroll
        for (int j = 0; j < 8; j++) {      // Whh2 ks 8..15
            W2H[j] = *(const short8*)(w2h_t + (size_t)(8 + j) * 512 + loff);
            W2L[j] = *(const short8*)(w2l_t + (size_t)(8 + j) * 512 + loff);
        }
    }

    // ---- zero A LDS; stage x_0 ----
    for (int i = tid; i < 32 * ASTR; i += 512) { (&A2h[0][0])[i] = 0; (&A2l[0][0])[i] = 0; }
    __syncthreads();
    {
        float v = x[((size_t)(bg * 32 + urow) * T_STEPS + 0) * 16 + ucol];
        unsigned short h = f2bf(v);
        A2h[urow][512 + ucol] = h;
        A2l[urow][512 + ucol] = f2bf(v - bf2f(h));
    }
    __syncthreads();

    float c1 = 0.f, c2 = 0.f;

#define AFRAG(AR, B) (*(const short8*)&AR[(B)])
#define GEMM6(Z0, Z1, BLK, WHR, WLR)                                            \
    {                                                                           \
        const int co = (BLK) * 32 + quad * 8;                                   \
        short8 ah0 = *(const short8*)&A2h[r16][co];                             \
        short8 al0 = *(const short8*)&A2l[r16][co];                             \
        short8 ah1 = *(const short8*)&A2h[r16 + 16][co];                        \
        short8 al1 = *(const short8*)&A2l[r16 + 16][co];                        \
        Z0 = MFMA16(ah0, WHR, Z0);  Z1 = MFMA16(ah1, WHR, Z1);                  \
        Z0 = MFMA16(al0, WHR, Z0);  Z1 = MFMA16(al1, WHR, Z1);                  \
        Z0 = MFMA16(ah0, WLR, Z0);  Z1 = MFMA16(ah1, WLR, Z1);                  \
    }

    for (int t = 0; t <= T_STEPS + 1; t++) {   // 367 bodies
        const int sa = (t + 1) & 1;   // h1_{t-1} LDS/global slot; also h2_{t-3} global slot
        const int sb = t & 1;         // h1_{t-2} LDS slot; publish slot for h1_t, h2_{t-2}

        // ===== S1: P1 GEMM: z1 = W1 . [h1_{t-1} | x_t] =====
        float4_ z0 = {0.f,0.f,0.f,0.f}, z1v = {0.f,0.f,0.f,0.f};
        if (kh == 0) {
#pragma unroll
            for (int j = 0; j < 5; j++) GEMM6(z0, z1v, sa * 8 + j, W1H[j], W1L[j])
        } else {
#pragma unroll
            for (int j = 0; j < 3; j++) GEMM6(z0, z1v, sa * 8 + 5 + j, W1H[j], W1L[j])
            GEMM6(z0, z1v, 16, W1H[3], W1L[3])   // x block (Wih1, ks 8)
        }
#pragma unroll
        for (int rr = 0; rr < 4; rr++) {
            zb[kh][quad * 4 + rr][g][r16]      = z0[rr];
            zb[kh][quad * 4 + rr + 16][g][r16] = z1v[rr];
        }
        __syncthreads();   // B1

        // ===== S2: h1 update+publish; x prefetch; h2_{t-3} restage =====
        if (t <= T_STEPS - 1) {
            float zi = zb[0][urow][0][ucol] + zb[1][urow][0][ucol] + bi1[0];
            float zf = zb[0][urow][1][ucol] + zb[1][urow][1][ucol] + bi1[1];
            float zg = zb[0][urow][2][ucol] + zb[1][urow][2][ucol] + bi1[2];
            float zo = zb[0][urow][3][ucol] + zb[1][urow][3][ucol] + bi1[3];
            c1 = sigm(zf) * c1 + sigm(zi) * tanh_(zg);
            float h = sigm(zo) * tanh_(c1);
            size_t o = (((size_t)sb * 16 + bg) * 32 + urow) * 256 + colg;
            __hip_atomic_store(&hb1[o], packhl(h), __ATOMIC_RELAXED, __HIP_MEMORY_SCOPE_AGENT);
        }
        {
            int tn = (t + 1 <= T_STEPS - 1) ? t + 1 : T_STEPS - 1;
            float v = x[((size_t)(bg * 32 + urow) * T_STEPS + tn) * 16 + ucol];
            unsigned short h = f2bf(v);
            A2h[urow][512 + ucol] = h;
            A2l[urow][512 + ucol] = f2bf(v - bf2f(h));
        }
        {   // h2_{t-3}: published by peers at end of body t-1 (RTT hidden by P1)
            poll_ge(cnt2, (u32)(16 * t));
            const u32* s2 = hb2 + (((size_t)sa * 16 + bg) * 32 + urow) * 256 + ucol * 16;
            stage16p(s2, &A2h[urow][544 + ucol * 16], &A2l[urow][544 + ucol * 16]);
        }
        __syncthreads();   // B2 (drains h1 publishes; H2/x staged)
        if (tid == 0)
            __hip_atomic_fetch_add(cnt1, 1u, __ATOMIC_RELAXED, __HIP_MEMORY_SCOPE_AGENT);

        // ===== S3: P2 GEMM: z2 = W2 . [h1_{t-2} | h2_{t-3}] =====
        float4_ y0 = {0.f,0.f,0.f,0.f}, y1v = {0.f,0.f,0.f,0.f};
        if (kh == 0) {
#pragma unroll
            for (int j = 0; j < 8; j++) GEMM6(y0, y1v, sb * 8 + j, W2H[j], W2L[j])
        } else {
#pragma unroll
            for (int j = 0; j < 8; j++) GEMM6(y0, y1v, 17 + j, W2H[j], W2L[j])
        }
#pragma unroll
        for (int rr = 0; rr < 4; rr++) {
            zb[kh][quad * 4 + rr][g][r16]      = y0[rr];
            zb[kh][quad * 4 + rr + 16][g][r16] = y1v[rr];
        }
        __syncthreads();   // B3

        // ===== S4: h2_{t-2} update+publish; h1_t restage (RTT hidden by P2) =====
        {
            float zi = zb[0][urow][0][ucol] + zb[1][urow][0][ucol] + bi2[0];
            float zf = zb[0][urow][1][ucol] + zb[1][urow][1][ucol] + bi2[1];
            float zg = zb[0][urow][2][ucol] + zb[1][urow][2][ucol] + bi2[2];
            float zo = zb[0][urow][3][ucol] + zb[1][urow][3][ucol] + bi2[3];
            float nc2 = sigm(zf) * c2 + sigm(zi) * tanh_(zg);
            float h = sigm(zo) * tanh_(nc2);
            if (t < 2) { nc2 = 0.f; h = 0.f; }   // h2_{-2}, h2_{-1} = 0
            c2 = nc2;
            size_t o = (((size_t)sb * 16 + bg) * 32 + urow) * 256 + colg;
            __hip_atomic_store(&hb2[o], packhl(h), __ATOMIC_RELAXED, __HIP_MEMORY_SCOPE_AGENT);
        }
        if (t <= T_STEPS - 1) {
            poll_ge(cnt1, (u32)(16 * (t + 1)));
            const u32* s1 = hb1 + (((size_t)sb * 16 + bg) * 32 + urow) * 256 + ucol * 16;
            stage16p(s1, &A2h[urow][sb * 256 + ucol * 16], &A2l[urow][sb * 256 + ucol * 16]);
        }
        __syncthreads();   // B4 (drains h2 publishes; h1 staged)
        if (tid == 0)
            __hip_atomic_fetch_add(cnt2, 1u, __ATOMIC_RELAXED, __HIP_MEMORY_SCOPE_AGENT);
    }

    // ---- head: wait all h2_364 published (body 366, slot 0), then reduce ----
    poll_ge(cnt2, (u32)(16 * (T_STEPS + 2)));
    __syncthreads();
    if (ns != 0) return;
    {
        int row = tid >> 4, seg = tid & 15;
        const u32* src = hb2 + ((size_t)bg * 32 + row) * 256 + seg * 16;   // slot 0
        float s = 0.f;
#pragma unroll
        for (int j = 0; j < 16; j++) {
            u32 v = __hip_atomic_load(&src[j], __ATOMIC_RELAXED, __HIP_MEMORY_SCOPE_AGENT);
            s += (bf2f((unsigned short)(v >> 16)) + bf2f((unsigned short)v)) * Wlin[seg * 16 + j];
        }
        hp[row][seg] = s;
    }
    __syncthreads();
    if (tid < 32) {
        float s = 0.f;
#pragma unroll
        for (int j = 0; j < 16; j++) s += hp[tid][j];
        out[bg * 32 + tid] = s + blin[0];
    }
}

extern "C" void kernel_launch(void* const* d_in, const int* in_sizes, int n_in,
                              void* d_out, int out_size, void* d_ws, size_t ws_size,
                              hipStream_t stream) {
    const float* x    = (const float*)d_in[0];
    const float* Wih1 = (const float*)d_in[1];
    const float* Whh1 = (const float*)d_in[2];
    const float* bih1 = (const float*)d_in[3];
    const float* bhh1 = (const float*)d_in[4];
    const float* Wih2 = (const float*)d_in[5];
    const float* Whh2 = (const float*)d_in[6];
    const float* bih2 = (const float*)d_in[7];
    const float* bhh2 = (const float*)d_in[8];
    const float* Wlin = (const float*)d_in[9];
    const float* blin = (const float*)d_in[10];
    float* out = (float*)d_out;

    char* pp = (char*)d_ws;
    unsigned short* w1h = (unsigned short*)pp; pp += (size_t)64 * 9 * 512 * 2;
    unsigned short* w1l = (unsigned short*)pp; pp += (size_t)64 * 9 * 512 * 2;
    unsigned short* w2h = (unsigned short*)pp; pp += (size_t)64 * 16 * 512 * 2;
    unsigned short* w2l = (unsigned short*)pp; pp += (size_t)64 * 16 * 512 * 2;
    float* bias1 = (float*)pp; pp += 1024 * 4;
    float* bias2 = (float*)pp; pp += 1024 * 4;
    char* zero_base = pp;
    u32* hb1 = (u32*)pp; pp += (size_t)2 * 16 * 32 * 256 * 4;   // 1 MB
    u32* hb2 = (u32*)pp; pp += (size_t)2 * 16 * 32 * 256 * 4;   // 1 MB
    u32* prog = (u32*)pp; pp += 16 * 32 * 4;                    // cnt1/cnt2 per bg
    size_t zero_bytes = (size_t)(pp - zero_base);

    hipMemsetAsync(zero_base, 0, zero_bytes, stream);
    prep_w<<<64, 256, 0, stream>>>(Wih1, Whh1, bih1, bhh1, Wih2, Whh2, bih2, bhh2,
                                   w1h, w1l, w2h, w2l, bias1, bias2);
    lstm_main<<<256, 512, 0, stream>>>(x, w1h, w1l, w2h, w2l, bias1, bias2,
                                       hb1, hb2, prog, Wlin, blin, out);
}

// Round 6
// 2747.692 us; speedup vs baseline: 1.0800x; 1.0800x over previous
//
#include <hip/hip_runtime.h>

// LSTM_38869454028951: B=512, T=365, F=16, H=256, 2 layers + linear head.
// Round 6: round-4 merged 3-barrier body + (a) forced weight residency via
// asm-opacity (compiler was re-streaming 200KB/CU/body from L2 -- VGPR=96),
// (b) gate-pair x K-quarter wave map (A-LDS redundancy 4->2, h1 A-frags feed
// both z1 and z2), (c) conflict-free zb [gate][kq][col][row+pad] float4.

#define T_STEPS 365
#define ASTR 552   // A row stride (ushorts); word stride 276 % 32 == 20 -> 2-way

typedef __attribute__((ext_vector_type(8))) short short8;
typedef __attribute__((ext_vector_type(8))) unsigned short ushort8;
typedef __attribute__((ext_vector_type(4))) float float4_;
typedef unsigned long long u64;
typedef unsigned int u32;

#define MFMA16(a, b, c) __builtin_amdgcn_mfma_f32_16x16x32_bf16((a), (b), (c), 0, 0, 0)
// zb layout: [gate 4][kq 4][col 16][row 36pad]  (36%4==0 for b128, 4*36%32!=0-ish)
#define ZBI(G, Q, C, R) (((((G) * 4 + (Q)) * 16 + (C)) * 36) + (R))

__device__ __forceinline__ unsigned short f2bf(float v) {
    union { float f; u32 u; } a; a.f = v;
    u32 r = a.u + 0x7fffu + ((a.u >> 16) & 1u);  // RNE
    return (unsigned short)(r >> 16);
}
__device__ __forceinline__ float bf2f(unsigned short h) {
    union { u32 u; float f; } a; a.u = ((u32)h) << 16; return a.f;
}
__device__ __forceinline__ u32 packhl(float v) {
    unsigned short hi = f2bf(v);
    unsigned short lo = f2bf(v - bf2f(hi));
    return ((u32)hi << 16) | (u32)lo;
}
__device__ __forceinline__ float sigm(float x)  { return 1.f / (1.f + __expf(-x)); }
__device__ __forceinline__ float tanh_(float x) { return 2.f / (1.f + __expf(-2.f * x)) - 1.f; }

__device__ __forceinline__ void poll_ge(u32* c, u32 tgt) {
    while (__hip_atomic_load(c, __ATOMIC_RELAXED, __HIP_MEMORY_SCOPE_AGENT) < tgt)
        __builtin_amdgcn_s_sleep(1);
}

// ---------------- prep: blocked hi/lo weights + biases ----------------
// w1blk: [64 tiles][9 ks][16 rows][32 k]; ks<8: Whh1; ks==8: Wih1 (K pad 16->32)
// w2blk: [64][16][16][32]; ks<8: Wih2 (h1 input), ks>=8: Whh2 (h2 input)
__global__ void prep_w(
    const float* __restrict__ Wih1, const float* __restrict__ Whh1,
    const float* __restrict__ bih1, const float* __restrict__ bhh1,
    const float* __restrict__ Wih2, const float* __restrict__ Whh2,
    const float* __restrict__ bih2, const float* __restrict__ bhh2,
    unsigned short* __restrict__ w1h, unsigned short* __restrict__ w1l,
    unsigned short* __restrict__ w2h, unsigned short* __restrict__ w2l,
    float* __restrict__ bias1, float* __restrict__ bias2)
{
    const int tile = blockIdx.x;          // 64
    const int g = tile >> 4, ns = tile & 15;
    const int tid = threadIdx.x;          // 256

    for (int idx = tid; idx < 9 * 512; idx += 256) {
        int ks = idx >> 9, off = idx & 511, r = off >> 5, kk = off & 31;
        int R = g * 256 + ns * 16 + r;
        float v;
        if (ks < 8)       v = Whh1[R * 256 + ks * 32 + kk];
        else if (kk < 16) v = Wih1[R * 16 + kk];
        else              v = 0.f;
        unsigned short h = f2bf(v);
        size_t d = (size_t)(tile * 9 + ks) * 512 + off;
        w1h[d] = h; w1l[d] = f2bf(v - bf2f(h));
    }
    for (int idx = tid; idx < 16 * 512; idx += 256) {
        int ks = idx >> 9, off = idx & 511, r = off >> 5, kk = off & 31;
        int R = g * 256 + ns * 16 + r;
        int k = ks * 32 + kk;
        float v = (k < 256) ? Wih2[R * 256 + k] : Whh2[R * 256 + (k - 256)];
        unsigned short h = f2bf(v);
        size_t d = (size_t)(tile * 16 + ks) * 512 + off;
        w2h[d] = h; w2l[d] = f2bf(v - bf2f(h));
    }
    if (tid < 16) {
        int R = g * 256 + ns * 16 + tid;
        bias1[R] = bih1[R] + bhh1[R];
        bias2[R] = bih2[R] + bhh2[R];
    }
}

// stage 16 packed u32 (8 agent u64 loads) -> bf16 hi/lo LDS (shift unpack)
__device__ __forceinline__ void stage16p(const u32* src, unsigned short* dh, unsigned short* dl) {
    ushort8 H0, H1, L0, L1;
#pragma unroll
    for (int j = 0; j < 4; j++) {
        u64 v = __hip_atomic_load((const u64*)src + j, __ATOMIC_RELAXED, __HIP_MEMORY_SCOPE_AGENT);
        u32 a = (u32)v, b = (u32)(v >> 32);
        H0[2 * j] = (unsigned short)(a >> 16);     L0[2 * j] = (unsigned short)a;
        H0[2 * j + 1] = (unsigned short)(b >> 16); L0[2 * j + 1] = (unsigned short)b;
    }
#pragma unroll
    for (int j = 0; j < 4; j++) {
        u64 v = __hip_atomic_load((const u64*)src + 4 + j, __ATOMIC_RELAXED, __HIP_MEMORY_SCOPE_AGENT);
        u32 a = (u32)v, b = (u32)(v >> 32);
        H1[2 * j] = (unsigned short)(a >> 16);     L1[2 * j] = (unsigned short)a;
        H1[2 * j + 1] = (unsigned short)(b >> 16); L1[2 * j + 1] = (unsigned short)b;
    }
    *(ushort8*)(dh) = H0; *(ushort8*)(dh + 8) = H1;
    *(ushort8*)(dl) = L0; *(ushort8*)(dl + 8) = L1;
}

// ---------------- main ----------------
__global__ __launch_bounds__(512, 2) void lstm_main(
    const float* __restrict__ x,
    const unsigned short* __restrict__ w1h, const unsigned short* __restrict__ w1l,
    const unsigned short* __restrict__ w2h, const unsigned short* __restrict__ w2l,
    const float* __restrict__ bias1, const float* __restrict__ bias2,
    u32* hb1, u32* hb2, u32* prog,
    const float* __restrict__ Wlin, const float* __restrict__ blin,
    float* __restrict__ out)
{
    // A cols: [0..255]=h1_{t-1}, [256..287]=x_t (272+ zero), [288..543]=h2_{t-2}
    __shared__ __align__(16) unsigned short A2h[32][ASTR];
    __shared__ __align__(16) unsigned short A2l[32][ASTR];
    __shared__ __align__(16) float zb1f[4 * 4 * 16 * 36];
    __shared__ __align__(16) float zb2f[4 * 4 * 16 * 36];
    __shared__ __align__(16) float hp[32][17];

    const int tid  = threadIdx.x;
    const int lane = tid & 63;
    const int wv   = tid >> 6;            // 8 waves
    const int quad = lane >> 4;
    const int r16  = lane & 15;
    const int kq   = wv & 3;              // K-quarter
    const int gp   = wv >> 2;             // gate pair: gates {2gp, 2gp+1}
    const int bg   = blockIdx.x & 15;     // batch group (same XCD for all 16 ns)
    const int ns   = blockIdx.x >> 4;     // col slice
    const int loff = r16 * 32 + quad * 8;

    const int urow = tid >> 4;            // updater: batch row 0..31
    const int ucol = tid & 15;            // local col 0..15
    const int colg = ns * 16 + ucol;      // global hidden col

    u32* cnt = prog + bg * 32;

    float bi1[4], bi2[4];
#pragma unroll
    for (int gg = 0; gg < 4; gg++) {
        bi1[gg] = bias1[gg * 256 + colg];
        bi2[gg] = bias2[gg * 256 + colg];
    }

    // ---- preload weights; force residency with asm opacity ----
    short8 W1H[2][3], W1L[2][3], W2H[2][4], W2L[2][4];
#pragma unroll
    for (int gg = 0; gg < 2; gg++) {
        const int tl = (gp * 2 + gg) * 16 + ns;
        const unsigned short* b1h = w1h + (size_t)tl * 9 * 512;
        const unsigned short* b1l = w1l + (size_t)tl * 9 * 512;
        const unsigned short* b2h = w2h + (size_t)tl * 16 * 512;
        const unsigned short* b2l = w2l + (size_t)tl * 16 * 512;
#pragma unroll
        for (int j = 0; j < 2; j++) {
            int ks = 2 * kq + j;
            W1H[gg][j] = *(const short8*)(b1h + (size_t)ks * 512 + loff);
            W1L[gg][j] = *(const short8*)(b1l + (size_t)ks * 512 + loff);
        }
        if (kq == 3) {   // x weights (Wih1, ks=8)
            W1H[gg][2] = *(const short8*)(b1h + (size_t)8 * 512 + loff);
            W1L[gg][2] = *(const short8*)(b1l + (size_t)8 * 512 + loff);
        } else {
            W1H[gg][2] = short8{0,0,0,0,0,0,0,0};
            W1L[gg][2] = short8{0,0,0,0,0,0,0,0};
        }
#pragma unroll
        for (int j = 0; j < 2; j++) {
            int ksA = 2 * kq + j;        // Wih2 (h1 input)
            int ksB = 8 + 2 * kq + j;    // Whh2 (h2 input)
            W2H[gg][j]     = *(const short8*)(b2h + (size_t)ksA * 512 + loff);
            W2L[gg][j]     = *(const short8*)(b2l + (size_t)ksA * 512 + loff);
            W2H[gg][2 + j] = *(const short8*)(b2h + (size_t)ksB * 512 + loff);
            W2L[gg][2 + j] = *(const short8*)(b2l + (size_t)ksB * 512 + loff);
        }
    }
#pragma unroll
    for (int gg = 0; gg < 2; gg++) {
#pragma unroll
        for (int j = 0; j < 2; j++)
            asm volatile("" : "+v"(W1H[gg][j]), "+v"(W1L[gg][j]));
#pragma unroll
        for (int j = 0; j < 4; j++)
            asm volatile("" : "+v"(W2H[gg][j]), "+v"(W2L[gg][j]));
    }
    if (kq == 3) {
#pragma unroll
        for (int gg = 0; gg < 2; gg++)
            asm volatile("" : "+v"(W1H[gg][2]), "+v"(W1L[gg][2]));
    }

    // ---- zero A LDS; stage x_0 ----
    for (int i = tid; i < 32 * ASTR; i += 512) { (&A2h[0][0])[i] = 0; (&A2l[0][0])[i] = 0; }
    __syncthreads();
    {
        float v = x[((size_t)(bg * 32 + urow) * T_STEPS + 0) * 16 + ucol];
        unsigned short h = f2bf(v);
        A2h[urow][256 + ucol] = h;
        A2l[urow][256 + ucol] = f2bf(v - bf2f(h));
    }
    __syncthreads();

    float c1 = 0.f, c2 = 0.f;

#define TERM3(A0, A1, WHR, WLR)                                \
    A0 = MFMA16(ah0, WHR, A0); A1 = MFMA16(ah1, WHR, A1);      \
    A0 = MFMA16(al0, WHR, A0); A1 = MFMA16(al1, WHR, A1);      \
    A0 = MFMA16(ah0, WLR, A0); A1 = MFMA16(ah1, WLR, A1);

    for (int t = 0; t <= T_STEPS; t++) {   // 366 bodies
        const int p = t & 1;

        // ================= merged GEMM (z1: K=288, z2: K=512) =================
        float4_ z1a[2][2] = {{{0.f,0.f,0.f,0.f},{0.f,0.f,0.f,0.f}},
                             {{0.f,0.f,0.f,0.f},{0.f,0.f,0.f,0.f}}};
        float4_ z2a[2][2] = {{{0.f,0.f,0.f,0.f},{0.f,0.f,0.f,0.f}},
                             {{0.f,0.f,0.f,0.f},{0.f,0.f,0.f,0.f}}};

#pragma unroll
        for (int j = 0; j < 2; j++) {      // h1 blocks: feed BOTH z1 and z2
            const int co = (2 * kq + j) * 32 + quad * 8;
            short8 ah0 = *(const short8*)&A2h[r16][co];
            short8 al0 = *(const short8*)&A2l[r16][co];
            short8 ah1 = *(const short8*)&A2h[r16 + 16][co];
            short8 al1 = *(const short8*)&A2l[r16 + 16][co];
#pragma unroll
            for (int gg = 0; gg < 2; gg++) {
                TERM3(z1a[gg][0], z1a[gg][1], W1H[gg][j], W1L[gg][j])
                TERM3(z2a[gg][0], z2a[gg][1], W2H[gg][j], W2L[gg][j])
            }
        }
        if (kq == 3) {                     // x block -> z1
            const int co = 256 + quad * 8;
            short8 ah0 = *(const short8*)&A2h[r16][co];
            short8 al0 = *(const short8*)&A2l[r16][co];
            short8 ah1 = *(const short8*)&A2h[r16 + 16][co];
            short8 al1 = *(const short8*)&A2l[r16 + 16][co];
#pragma unroll
            for (int gg = 0; gg < 2; gg++) {
                TERM3(z1a[gg][0], z1a[gg][1], W1H[gg][2], W1L[gg][2])
            }
        }
#pragma unroll
        for (int j = 0; j < 2; j++) {      // h2 blocks -> z2
            const int co = 288 + (2 * kq + j) * 32 + quad * 8;
            short8 ah0 = *(const short8*)&A2h[r16][co];
            short8 al0 = *(const short8*)&A2l[r16][co];
            short8 ah1 = *(const short8*)&A2h[r16 + 16][co];
            short8 al1 = *(const short8*)&A2l[r16 + 16][co];
#pragma unroll
            for (int gg = 0; gg < 2; gg++) {
                TERM3(z2a[gg][0], z2a[gg][1], W2H[gg][2 + j], W2L[gg][2 + j])
            }
        }

#pragma unroll
        for (int gg = 0; gg < 2; gg++) {
            const int gate = gp * 2 + gg;
            *(float4_*)&zb1f[ZBI(gate, kq, r16, quad * 4)]      = z1a[gg][0];
            *(float4_*)&zb1f[ZBI(gate, kq, r16, 16 + quad * 4)] = z1a[gg][1];
            *(float4_*)&zb2f[ZBI(gate, kq, r16, quad * 4)]      = z2a[gg][0];
            *(float4_*)&zb2f[ZBI(gate, kq, r16, 16 + quad * 4)] = z2a[gg][1];
        }
        __syncthreads();   // B1: zb ready; all A reads done

        // ---- reduce 4 kq partials; update h1_t and h2_{t-1}; publish ----
        {
            float zg1[4], zg2[4];
#pragma unroll
            for (int g4 = 0; g4 < 4; g4++) {
                float s1 = bi1[g4], s2 = bi2[g4];
#pragma unroll
                for (int q = 0; q < 4; q++) {
                    s1 += zb1f[ZBI(g4, q, ucol, urow)];
                    s2 += zb2f[ZBI(g4, q, ucol, urow)];
                }
                zg1[g4] = s1; zg2[g4] = s2;
            }
            // layer 1 -> h1_t
            c1 = sigm(zg1[1]) * c1 + sigm(zg1[0]) * tanh_(zg1[2]);
            float h1v = sigm(zg1[3]) * tanh_(c1);
            size_t o1 = (((size_t)p * 16 + bg) * 32 + urow) * 256 + colg;
            __hip_atomic_store(&hb1[o1], packhl(h1v), __ATOMIC_RELAXED, __HIP_MEMORY_SCOPE_AGENT);
            // layer 2 -> h2_{t-1} (retimed)
            float nc2 = sigm(zg2[1]) * c2 + sigm(zg2[0]) * tanh_(zg2[2]);
            float h2v = sigm(zg2[3]) * tanh_(nc2);
            if (t == 0) { nc2 = 0.f; h2v = 0.f; }   // h2_{-1} = 0
            c2 = nc2;
            size_t o2 = (((size_t)(1 - p) * 16 + bg) * 32 + urow) * 256 + colg;
            __hip_atomic_store(&hb2[o2], packhl(h2v), __ATOMIC_RELAXED, __HIP_MEMORY_SCOPE_AGENT);
        }
        __syncthreads();   // B2: publishes drained (vmcnt 0 at barrier)

        if (tid == 0)
            __hip_atomic_fetch_add(cnt, 1u, __ATOMIC_RELAXED, __HIP_MEMORY_SCOPE_AGENT);

        // ---- prefetch x_{t+1} into A block 8 (own LDS; GEMM reads done) ----
        {
            int tn = (t + 1 <= T_STEPS - 1) ? t + 1 : T_STEPS - 1;
            float v = x[((size_t)(bg * 32 + urow) * T_STEPS + tn) * 16 + ucol];
            unsigned short h = f2bf(v);
            A2h[urow][256 + ucol] = h;
            A2l[urow][256 + ucol] = f2bf(v - bf2f(h));
        }

        // ---- wait peers done body t; restage h1_t and h2_{t-1} ----
        poll_ge(cnt, (u32)(16 * (t + 1)));
        {
            const u32* s1 = hb1 + (((size_t)p * 16 + bg) * 32 + urow) * 256 + ucol * 16;
            const u32* s2 = hb2 + (((size_t)(1 - p) * 16 + bg) * 32 + urow) * 256 + ucol * 16;
            stage16p(s1, &A2h[urow][ucol * 16],       &A2l[urow][ucol * 16]);
            stage16p(s2, &A2h[urow][288 + ucol * 16], &A2l[urow][288 + ucol * 16]);
        }
        __syncthreads();   // B3: A ready for next body
    }

    // ---- head (ns==0): out[b] = h2_364 . Wlin + blin ; h2_364 in slot 0 ----
    if (ns != 0) return;
    {
        int row = tid >> 4, seg = tid & 15;
        const u32* src = hb2 + ((size_t)bg * 32 + row) * 256 + seg * 16;   // slot 0
        float s = 0.f;
#pragma unroll
        for (int j = 0; j < 16; j++) {
            u32 v = __hip_atomic_load(&src[j], __ATOMIC_RELAXED, __HIP_MEMORY_SCOPE_AGENT);
            s += (bf2f((unsigned short)(v >> 16)) + bf2f((unsigned short)v)) * Wlin[seg * 16 + j];
        }
        hp[row][seg] = s;
    }
    __syncthreads();
    if (tid < 32) {
        float s = 0.f;
#pragma unroll
        for (int j = 0; j < 16; j++) s += hp[tid][j];
        out[bg * 32 + tid] = s + blin[0];
    }
}

extern "C" void kernel_launch(void* const* d_in, const int* in_sizes, int n_in,
                              void* d_out, int out_size, void* d_ws, size_t ws_size,
                              hipStream_t stream) {
    const float* x    = (const float*)d_in[0];
    const float* Wih1 = (const float*)d_in[1];
    const float* Whh1 = (const float*)d_in[2];
    const float* bih1 = (const float*)d_in[3];
    const float* bhh1 = (const float*)d_in[4];
    const float* Wih2 = (const float*)d_in[5];
    const float* Whh2 = (const float*)d_in[6];
    const float* bih2 = (const float*)d_in[7];
    const float* bhh2 = (const float*)d_in[8];
    const float* Wlin = (const float*)d_in[9];
    const float* blin = (const float*)d_in[10];
    float* out = (float*)d_out;

    char* pp = (char*)d_ws;
    unsigned short* w1h = (unsigned short*)pp; pp += (size_t)64 * 9 * 512 * 2;
    unsigned short* w1l = (unsigned short*)pp; pp += (size_t)64 * 9 * 512 * 2;
    unsigned short* w2h = (unsigned short*)pp; pp += (size_t)64 * 16 * 512 * 2;
    unsigned short* w2l = (unsigned short*)pp; pp += (size_t)64 * 16 * 512 * 2;
    float* bias1 = (float*)pp; pp += 1024 * 4;
    float* bias2 = (float*)pp; pp += 1024 * 4;
    char* zero_base = pp;
    u32* hb1 = (u32*)pp; pp += (size_t)2 * 16 * 32 * 256 * 4;   // 1 MB
    u32* hb2 = (u32*)pp; pp += (size_t)2 * 16 * 32 * 256 * 4;   // 1 MB
    u32* prog = (u32*)pp; pp += 16 * 32 * 4;                    // 1 counter/bg, 128B apart
    size_t zero_bytes = (size_t)(pp - zero_base);

    hipMemsetAsync(zero_base, 0, zero_bytes, stream);
    prep_w<<<64, 256, 0, stream>>>(Wih1, Whh1, bih1, bhh1, Wih2, Whh2, bih2, bhh2,
                                   w1h, w1l, w2h, w2l, bias1, bias2);
    lstm_main<<<256, 512, 0, stream>>>(x, w1h, w1l, w2h, w2l, bias1, bias2,
                                       hb1, hb2, prog, Wlin, blin, out);
}